// Round 1
// baseline (606.177 us; speedup 1.0000x reference)
//
#include <hip/hip_runtime.h>
#include <hip/hip_bf16.h>

// 3-layer GCN: per layer  out = relu(dinv .* segsum(dinv .* (X@W)) + b)
// fp16 pipeline: GEMMs via mfma_f32_16x16x32_f16 (f32 accum).
//  - GEMM: waves own DISJOINT 16-row strips x all FOUT cols; B staged to LDS
//    ONCE per block; W pre-stored in MFMA fragment order.
//  - Feature matrices between layers are CHUNK-MAJOR [NCHUNK][N][16] fp16:
//    each 16-feat chunk table is 3.2 MB and is gathered by exactly one XCD
//    (chunk = blockIdx%8 -> HW round-robin XCD), so the random src-row reads
//    are served from the 4 MB per-XCD L2 instead of the ~3 TB/s TCC-miss
//    path that bound the previous row-major gather (FETCH 190 MB @ 3.45 TB/s).
//    eidx / outputs use nontemporal access so streams don't evict the table.
// CSR build = deterministic two-level counting sort, zero global atomics.

#define NNODES 100000
#define NB 391          // buckets of 256 nodes: ceil(100000/256)
#define PB 2048         // edges per partition block
#define BCAP 12288      // per-bucket LDS sort capacity (mean 4096, sd ~64)

typedef _Float16 half8  __attribute__((ext_vector_type(8)));
typedef _Float16 half4v __attribute__((ext_vector_type(4)));
typedef float    floatx4 __attribute__((ext_vector_type(4)));

static __device__ __forceinline__ floatx4 h2f4(half4v v) {
    return (floatx4){(float)v.x, (float)v.y, (float)v.z, (float)v.w};
}

// ---------------- CSR build: deterministic partition ----------------
__global__ __launch_bounds__(256) void blockhist_k(const int* __restrict__ dst,
                                                   int* __restrict__ H, int e) {
    __shared__ int h[NB];
    for (int q = threadIdx.x; q < NB; q += 256) h[q] = 0;
    __syncthreads();
    int base = blockIdx.x * PB;
    int lim = e - base; if (lim > PB) lim = PB;
    for (int i = threadIdx.x; i < lim; i += 256)
        atomicAdd(&h[dst[base + i] >> 8], 1);
    __syncthreads();
    for (int q = threadIdx.x; q < NB; q += 256)
        H[(size_t)blockIdx.x * NB + q] = h[q];
}

__global__ __launch_bounds__(256) void bucketscan_k(const int* __restrict__ H,
                                                    int* __restrict__ O,
                                                    int* __restrict__ T, int npb) {
    __shared__ int lds[256];
    int b = blockIdx.x, t = threadIdx.x;
    int running = 0;
    for (int c0 = 0; c0 < npb; c0 += 256) {
        int idx = c0 + t;
        int v = (idx < npb) ? H[(size_t)idx * NB + b] : 0;
        lds[t] = v;
        __syncthreads();
        #pragma unroll
        for (int off = 1; off < 256; off <<= 1) {
            int u = (t >= off) ? lds[t - off] : 0;
            __syncthreads();
            lds[t] += u;
            __syncthreads();
        }
        int excl = lds[t] - v + running;
        if (idx < npb) O[(size_t)idx * NB + b] = excl;
        running += lds[255];
        __syncthreads();
    }
    if (t == 0) T[b] = running;
}

__global__ __launch_bounds__(512) void scanT_k(const int* __restrict__ T,
                                               int* __restrict__ bbase, int e) {
    __shared__ int lds[512];
    int t = threadIdx.x;
    int v = (t < NB) ? T[t] : 0;
    lds[t] = v;
    __syncthreads();
    #pragma unroll
    for (int off = 1; off < 512; off <<= 1) {
        int u = (t >= off) ? lds[t - off] : 0;
        __syncthreads();
        lds[t] += u;
        __syncthreads();
    }
    if (t < NB) bbase[t] = lds[t] - v;
    if (t == 0) bbase[NB] = e;
}

__global__ __launch_bounds__(256) void scatter_k(const int* __restrict__ src,
                                                 const int* __restrict__ dst,
                                                 const int* __restrict__ O,
                                                 const int* __restrict__ bbase,
                                                 unsigned* __restrict__ binned, int e) {
    __shared__ int cur[NB];
    for (int q = threadIdx.x; q < NB; q += 256)
        cur[q] = bbase[q] + O[(size_t)blockIdx.x * NB + q];
    __syncthreads();
    int base = blockIdx.x * PB;
    int lim = e - base; if (lim > PB) lim = PB;
    for (int i = threadIdx.x; i < lim; i += 256) {
        int d = dst[base + i];
        int s = src[base + i];
        int p = atomicAdd(&cur[d >> 8], 1);
        binned[p] = ((unsigned)(d & 255) << 17) | (unsigned)s;
    }
}

__global__ __launch_bounds__(256) void bucket_fill_k(
    const unsigned* __restrict__ binned, const int* __restrict__ bbase,
    int* __restrict__ rowptr, int* __restrict__ eidx,
    float* __restrict__ dinv, int n, int e) {
    __shared__ int cnt[256];
    __shared__ int cur[256];
    __shared__ int lds[256];
    __shared__ int sbuf[BCAP];
    int b = blockIdx.x, t = threadIdx.x;
    int beg = bbase[b], end = bbase[b + 1];
    int m = end - beg;
    cnt[t] = 0;
    __syncthreads();
    for (int q = t; q < m; q += 256) {
        unsigned r = binned[beg + q];
        atomicAdd(&cnt[r >> 17], 1);
    }
    __syncthreads();
    int v = cnt[t];
    lds[t] = v;
    __syncthreads();
    #pragma unroll
    for (int off = 1; off < 256; off <<= 1) {
        int u = (t >= off) ? lds[t - off] : 0;
        __syncthreads();
        lds[t] += u;
        __syncthreads();
    }
    int excl = lds[t] - v;
    int node = b * 256 + t;
    if (node < n) {
        rowptr[node] = beg + excl;
        dinv[node] = rsqrtf(1.0f + (float)v);
    }
    if (b == NB - 1 && t == 0) rowptr[n] = e;
    cur[t] = excl;
    __syncthreads();
    for (int q = t; q < m; q += 256) {
        unsigned r = binned[beg + q];
        int p = atomicAdd(&cur[r >> 17], 1);
        if (p < BCAP) sbuf[p] = (int)(r & 0x1FFFFu);
    }
    __syncthreads();
    for (int q = t; q < m; q += 256) eidx[beg + q] = sbuf[q];
}

// ------- W cast to fp16 in MFMA fragment order (once) -------
// frag idx for element (k,n): ct=n>>4, mrow=n&15, kc=k>>5, hi=(k&31)>>3, j=k&7
// idx = ((ct*NKC+kc)*64 + hi*16+mrow)*8 + j   (NKC = FIN/32)
static __device__ __forceinline__ void cast_frag(
    const float* __restrict__ W, _Float16* __restrict__ Wf,
    int FIN, int FOUT, int i) {
    int k = i / FOUT, n = i % FOUT;
    int ct = n >> 4, mrow = n & 15;
    int kc = k >> 5, hi = (k & 31) >> 3, j = k & 7;
    int NKC = FIN / 32;
    int idx = ((ct * NKC + kc) * 64 + hi * 16 + mrow) * 8 + j;
    Wf[idx] = (_Float16)W[(size_t)k * FOUT + n];
}

__global__ __launch_bounds__(256) void castW_k(
    const float* __restrict__ W1, const float* __restrict__ W2,
    const float* __restrict__ W3, _Float16* __restrict__ Wf1,
    _Float16* __restrict__ Wf2, _Float16* __restrict__ Wf3) {
    int i = blockIdx.x * 256 + threadIdx.x;
    if (i < 256 * 128) cast_frag(W1, Wf1, 256, 128, i);
    if (i < 128 * 128) cast_frag(W2, Wf2, 128, 128, i);
    if (i < 128 * 64)  cast_frag(W3, Wf3, 128, 64, i);
}

// ------- GEMM: G(fp16, chunk-major) = (X@W)*dinv[row] -------
// block = 4 waves x 16 rows = 64 rows, all FOUT cols per wave.
// B (fragment-ordered) staged to LDS once (memcpy); one barrier total.
// fp16 input X is chunk-major [FIN/16][n][16]; output G is chunk-major
// [FOUT/16][n][16] (ct IS the chunk index in the MFMA D layout).
template<typename TA, int FIN, int FOUT>
__global__ __launch_bounds__(256, 2) void gemm_ldsB_k(
    const TA* __restrict__ X, const _Float16* __restrict__ Wf,
    const float* __restrict__ dinv, _Float16* __restrict__ G, int n)
{
    constexpr int NKC = FIN / 32;        // k-chunks
    constexpr int NCT = FOUT / 16;       // col tiles (all owned by each wave)
    __shared__ _Float16 wS[FOUT * FIN];  // 64/32/16 KB

    const int tid  = threadIdx.x;
    const int wave = tid >> 6;
    const int lane = tid & 63;
    const int mrow = lane & 15;
    const int kq   = (lane >> 4) * 8;

    // stage fragment-ordered W -> LDS (contiguous memcpy)
    {
        const half8* s = (const half8*)Wf;
        half8* d = (half8*)wS;
        constexpr int TOT8 = FOUT * FIN / 8;
        #pragma unroll
        for (int i = tid; i < TOT8; i += 256) d[i] = s[i];
    }

    int r = blockIdx.x * 64 + wave * 16 + mrow;
    if (r > n - 1) r = n - 1;            // junk rows never stored

    // all A-loads upfront (independent, overlap the staging + barrier)
    half8 af[NKC];
    if constexpr (sizeof(TA) == 4) {
        // row-major fp32 input (layer 1: x)
        const float* xp = (const float*)X + (size_t)r * FIN + kq;
        float4 t0[NKC], t1[NKC];
        #pragma unroll
        for (int kc = 0; kc < NKC; ++kc) {
            t0[kc] = *(const float4*)(xp + kc * 32);
            t1[kc] = *(const float4*)(xp + kc * 32 + 4);
        }
        #pragma unroll
        for (int kc = 0; kc < NKC; ++kc) {
            float4 u0 = t0[kc], u1 = t1[kc];
            af[kc] = (half8){(_Float16)u0.x, (_Float16)u0.y, (_Float16)u0.z, (_Float16)u0.w,
                             (_Float16)u1.x, (_Float16)u1.y, (_Float16)u1.z, (_Float16)u1.w};
        }
    } else {
        // chunk-major fp16 input [FIN/16][n][16]: 8 needed halfs are
        // contiguous within one chunk row (off = 0 or 8)
        const _Float16* xp = (const _Float16*)X;
        #pragma unroll
        for (int kc = 0; kc < NKC; ++kc) {
            int f0 = kc * 32 + kq;
            af[kc] = *(const half8*)(xp + ((size_t)(f0 >> 4) * n + r) * 16 + (f0 & 15));
        }
    }

    __syncthreads();                     // the only barrier

    floatx4 acc[NCT];
    #pragma unroll
    for (int ct = 0; ct < NCT; ++ct) acc[ct] = (floatx4){0.f, 0.f, 0.f, 0.f};

    #pragma unroll
    for (int kc = 0; kc < NKC; ++kc) {
        #pragma unroll
        for (int ct = 0; ct < NCT; ++ct) {
            // stride-1 ds_read_b128: addr = ((ct*NKC+kc)*64 + lane)*16B
            half8 bf = *(const half8*)&wS[(((ct * NKC) + kc) * 64 + lane) * 8];
            acc[ct] = __builtin_amdgcn_mfma_f32_16x16x32_f16(af[kc], bf, acc[ct], 0, 0, 0);
        }
    }

    // D layout: col = lane&15, row = (lane>>4)*4 + reg  [m89/m91 verified]
    int rbase = blockIdx.x * 64 + wave * 16 + (lane >> 4) * 4;
    #pragma unroll
    for (int reg = 0; reg < 4; ++reg) {
        int rr = rbase + reg;
        if (rr < n) {
            float s = dinv[rr];
            #pragma unroll
            for (int ct = 0; ct < NCT; ++ct)
                G[((size_t)ct * n + rr) * 16 + mrow] = (_Float16)(acc[ct][reg] * s);
        }
    }
}

// -------- Chunk-major XCD-local gather --------
// g layout [NCHUNK][n][16] fp16. blockIdx%8 selects the feature chunk (and the
// node half when NCHUNK==4); consecutive blockIdx round-robin the 8 XCDs, so
// each XCD's 4 MB L2 caches exactly ONE 3.2 MB chunk table and the random
// src-row gathers hit L2. eidx is streamed nontemporally (read once per XCD),
// outputs are nt-stored, so neither evicts the resident table.
// Wave structure: 4 nodes per wave (one per 16-lane quarter); within a
// quarter: 4 edge-groups x 4 feat-lanes, 16 edge ids loaded coalesced then
// shfl-broadcast; 4 row-loads in flight; 2-round butterfly reduce.
template<int NCHUNK, bool RELU, bool F32OUT>
__global__ __launch_bounds__(256) void gatherchunk_k(
    const _Float16* __restrict__ g, const int* __restrict__ rowptr,
    const int* __restrict__ eidx, const float* __restrict__ dinv,
    const float* __restrict__ bias, void* __restrict__ outv, int n)
{
    const int lane    = threadIdx.x & 63;
    const int wave    = threadIdx.x >> 6;
    const int quarter = lane >> 4;      // node slot within wave
    const int ql      = lane & 15;
    const int grp     = ql >> 2;        // 4 edge groups per node
    const int q       = ql & 3;         // feats 4q..4q+3 of this chunk

    const int cg = blockIdx.x & 7;      // -> XCD (HW round-robin)
    const int nb = blockIdx.x >> 3;
    int chunk, n0, nlim;
    if constexpr (NCHUNK == 8) {
        chunk = cg; n0 = 0; nlim = n;
    } else {
        chunk = cg & 3;
        int hh = (n + 1) >> 1;
        n0   = (cg >> 2) ? hh : 0;
        nlim = (cg >> 2) ? n  : hh;
    }
    const _Float16* __restrict__ gc = g + (size_t)chunk * n * 16;
    const float4 bb = *(const float4*)(bias + chunk * 16 + 4 * q);

    const int node = n0 + nb * 16 + wave * 4 + quarter;
    if (node >= nlim) return;           // quarter-uniform; shfl stays in-quarter

    const int beg = rowptr[node];
    const int end = rowptr[node + 1];
    const float sc = dinv[node];

    floatx4 acc = {0.f, 0.f, 0.f, 0.f};
    {   // self loop: g row already carries one dinv, final *sc gives dinv^2
        half4v v = *(const half4v*)(gc + ((node << 4) | (q << 2)));
        if (grp == 0) acc = h2f4(v);
    }

    for (int j0 = beg; j0 < end; j0 += 16) {
        int m = end - j0; if (m > 16) m = 16;
        int id = (ql < m) ? __builtin_nontemporal_load(eidx + j0 + ql) : 0;
        #pragma unroll
        for (int t = 0; t < 16; t += 4) {
            int e = t + grp;
            int src = __shfl(id, (lane & 48) + e);   // in-quarter broadcast
            // unconditional load (src==0 for dead slots: safe addr, pipelined)
            half4v v = *(const half4v*)(gc + ((src << 4) | (q << 2)));
            if (e < m) acc += h2f4(v);
        }
    }

    // reduce the 4 edge-groups (butterfly within the quarter)
    #pragma unroll
    for (int off = 4; off <= 8; off <<= 1) {
        acc.x += __shfl_xor(acc.x, off);
        acc.y += __shfl_xor(acc.y, off);
        acc.z += __shfl_xor(acc.z, off);
        acc.w += __shfl_xor(acc.w, off);
    }

    if (grp == 0) {
        float o0 = fmaf(acc.x, sc, bb.x);
        float o1 = fmaf(acc.y, sc, bb.y);
        float o2 = fmaf(acc.z, sc, bb.z);
        float o3 = fmaf(acc.w, sc, bb.w);
        if (RELU) {
            o0 = fmaxf(o0, 0.f); o1 = fmaxf(o1, 0.f);
            o2 = fmaxf(o2, 0.f); o3 = fmaxf(o3, 0.f);
        }
        if constexpr (F32OUT) {
            // final output: row-major [n][NCHUNK*16] fp32 (harness layout)
            floatx4* p = (floatx4*)((float*)outv + (size_t)node * (NCHUNK * 16)
                                    + chunk * 16 + 4 * q);
            __builtin_nontemporal_store((floatx4){o0, o1, o2, o3}, p);
        } else {
            // chunk-major fp16 out (next GEMM's A)
            half4v hv = {(_Float16)o0, (_Float16)o1, (_Float16)o2, (_Float16)o3};
            half4v* p = (half4v*)outv + ((size_t)chunk * n + node) * 4 + q;
            __builtin_nontemporal_store(hv, p);
        }
    }
}

extern "C" void kernel_launch(void* const* d_in, const int* in_sizes, int n_in,
                              void* d_out, int out_size, void* d_ws, size_t ws_size,
                              hipStream_t stream) {
    const float* x  = (const float*)d_in[0];
    const int*   ei = (const int*)d_in[1];     // [2, E] int32
    const float* W1 = (const float*)d_in[2];
    const float* b1 = (const float*)d_in[3];
    const float* W2 = (const float*)d_in[4];
    const float* b2 = (const float*)d_in[5];
    const float* W3 = (const float*)d_in[6];
    const float* b3 = (const float*)d_in[7];
    float* out = (float*)d_out;

    const int N = NNODES;
    const int E = in_sizes[1] / 2;
    const int* srcI = ei;
    const int* dstI = ei + E;

    const int npb = (E + PB - 1) / PB;

    char* ws = (char*)d_ws;
    size_t p = 0;
    auto alloc = [&](size_t bytes) { void* r = ws + p; p = (p + bytes + 255) & ~(size_t)255; return r; };
    float*     dinv   = (float*)    alloc((size_t)N * 4);
    int*       rowptr = (int*)      alloc((size_t)(N + 1) * 4);
    int*       bbase  = (int*)      alloc((size_t)(NB + 1) * 4);
    int*       T      = (int*)      alloc((size_t)NB * 4);
    int*       H      = (int*)      alloc((size_t)npb * NB * 4);
    int*       O      = (int*)      alloc((size_t)npb * NB * 4);
    unsigned*  binned = (unsigned*) alloc((size_t)E * 4);
    int*       eidx   = (int*)      alloc((size_t)E * 4);
    _Float16*  Wf1    = (_Float16*) alloc((size_t)128 * 256 * 2);
    _Float16*  Wf2    = (_Float16*) alloc((size_t)128 * 128 * 2);
    _Float16*  Wf3    = (_Float16*) alloc((size_t)64 * 128 * 2);
    _Float16*  A      = (_Float16*) alloc((size_t)N * 128 * 2);
    _Float16*  Ch     = (_Float16*) alloc((size_t)N * 128 * 2);

    const int nb_gemm  = (N + 63) / 64;                 // 1563 blocks, 64 rows each
    const int nb_gc128 = ((N + 15) / 16) * 8;           // 6250 node-blocks x 8 chunks
    const int nb_gc64  = (((N + 1) / 2 + 15) / 16) * 8; // 3125 x (4 chunks x 2 halves)

    // ---- CSR build + weight prep ----
    blockhist_k<<<npb, 256, 0, stream>>>(dstI, H, E);
    castW_k<<<128, 256, 0, stream>>>(W1, W2, W3, Wf1, Wf2, Wf3);
    bucketscan_k<<<NB, 256, 0, stream>>>(H, O, T, npb);
    scanT_k<<<1, 512, 0, stream>>>(T, bbase, E);
    scatter_k<<<npb, 256, 0, stream>>>(srcI, dstI, O, bbase, binned, E);
    bucket_fill_k<<<NB, 256, 0, stream>>>(binned, bbase, rowptr, eidx, dinv, N, E);

    // ---- layer 1: FEAT=256 -> HID=128 ----
    gemm_ldsB_k<float, 256, 128><<<nb_gemm, 256, 0, stream>>>(x, Wf1, dinv, A, N);
    gatherchunk_k<8, true, false><<<nb_gc128, 256, 0, stream>>>(A, rowptr, eidx, dinv, b1, Ch, N);

    // ---- layer 2: HID=128 -> HID=128 ----
    gemm_ldsB_k<_Float16, 128, 128><<<nb_gemm, 256, 0, stream>>>(Ch, Wf2, dinv, A, N);
    gatherchunk_k<8, true, false><<<nb_gc128, 256, 0, stream>>>(A, rowptr, eidx, dinv, b2, Ch, N);

    // ---- layer 3: HID=128 -> OUT=64 ----
    gemm_ldsB_k<_Float16, 128, 64><<<nb_gemm, 256, 0, stream>>>(Ch, Wf3, dinv, A, N);
    gatherchunk_k<4, false, true><<<nb_gc64, 256, 0, stream>>>(A, rowptr, eidx, dinv, b3, out, N);
}

// Round 2
// 602.694 us; speedup vs baseline: 1.0058x; 1.0058x over previous
//
#include <hip/hip_runtime.h>
#include <hip/hip_bf16.h>

// 3-layer GCN: per layer  out = relu(dinv .* segsum(dinv .* (X@W)) + b)
// fp16 pipeline: GEMMs via mfma_f32_16x16x32_f16 (f32 accum).
//  - GEMM: waves own DISJOINT 16-row strips x all FOUT cols; B staged to LDS
//    ONCE per block; W pre-stored in MFMA fragment order.
//  - Feature matrices between layers are CHUNK-MAJOR [NCHUNK][N][32] fp16:
//    32-feat chunks = 64 B rows, so every gather row-read is a single fully
//    used 64 B line (4 line-touches/edge, same as row-major — the 16-feat
//    version's 32 B rows hit a ~1 req/cy/CU L1 transaction ceiling at 130 us).
//    chunk = blockIdx%NCHUNK -> HW round-robin XCDs: per-XCD gather working
//    set is one 6.4 MB chunk table vs 25.6 MB row-major, cutting the 3.45 TB/s
//    TCC-fetch traffic that bound the 63.7 us row-major gather.
//    eidx / outputs use nontemporal access so streams don't evict the table.
// CSR build = deterministic two-level counting sort, zero global atomics.

#define NNODES 100000
#define NB 391          // buckets of 256 nodes: ceil(100000/256)
#define PB 2048         // edges per partition block
#define BCAP 12288      // per-bucket LDS sort capacity (mean 4096, sd ~64)

typedef _Float16 half8  __attribute__((ext_vector_type(8)));
typedef _Float16 half4v __attribute__((ext_vector_type(4)));
typedef float    floatx4 __attribute__((ext_vector_type(4)));

static __device__ __forceinline__ floatx4 h2f4(half4v v) {
    return (floatx4){(float)v.x, (float)v.y, (float)v.z, (float)v.w};
}

// ---------------- CSR build: deterministic partition ----------------
__global__ __launch_bounds__(256) void blockhist_k(const int* __restrict__ dst,
                                                   int* __restrict__ H, int e) {
    __shared__ int h[NB];
    for (int q = threadIdx.x; q < NB; q += 256) h[q] = 0;
    __syncthreads();
    int base = blockIdx.x * PB;
    int lim = e - base; if (lim > PB) lim = PB;
    for (int i = threadIdx.x; i < lim; i += 256)
        atomicAdd(&h[dst[base + i] >> 8], 1);
    __syncthreads();
    for (int q = threadIdx.x; q < NB; q += 256)
        H[(size_t)blockIdx.x * NB + q] = h[q];
}

__global__ __launch_bounds__(256) void bucketscan_k(const int* __restrict__ H,
                                                    int* __restrict__ O,
                                                    int* __restrict__ T, int npb) {
    __shared__ int lds[256];
    int b = blockIdx.x, t = threadIdx.x;
    int running = 0;
    for (int c0 = 0; c0 < npb; c0 += 256) {
        int idx = c0 + t;
        int v = (idx < npb) ? H[(size_t)idx * NB + b] : 0;
        lds[t] = v;
        __syncthreads();
        #pragma unroll
        for (int off = 1; off < 256; off <<= 1) {
            int u = (t >= off) ? lds[t - off] : 0;
            __syncthreads();
            lds[t] += u;
            __syncthreads();
        }
        int excl = lds[t] - v + running;
        if (idx < npb) O[(size_t)idx * NB + b] = excl;
        running += lds[255];
        __syncthreads();
    }
    if (t == 0) T[b] = running;
}

__global__ __launch_bounds__(512) void scanT_k(const int* __restrict__ T,
                                               int* __restrict__ bbase, int e) {
    __shared__ int lds[512];
    int t = threadIdx.x;
    int v = (t < NB) ? T[t] : 0;
    lds[t] = v;
    __syncthreads();
    #pragma unroll
    for (int off = 1; off < 512; off <<= 1) {
        int u = (t >= off) ? lds[t - off] : 0;
        __syncthreads();
        lds[t] += u;
        __syncthreads();
    }
    if (t < NB) bbase[t] = lds[t] - v;
    if (t == 0) bbase[NB] = e;
}

__global__ __launch_bounds__(256) void scatter_k(const int* __restrict__ src,
                                                 const int* __restrict__ dst,
                                                 const int* __restrict__ O,
                                                 const int* __restrict__ bbase,
                                                 unsigned* __restrict__ binned, int e) {
    __shared__ int cur[NB];
    for (int q = threadIdx.x; q < NB; q += 256)
        cur[q] = bbase[q] + O[(size_t)blockIdx.x * NB + q];
    __syncthreads();
    int base = blockIdx.x * PB;
    int lim = e - base; if (lim > PB) lim = PB;
    for (int i = threadIdx.x; i < lim; i += 256) {
        int d = dst[base + i];
        int s = src[base + i];
        int p = atomicAdd(&cur[d >> 8], 1);
        binned[p] = ((unsigned)(d & 255) << 17) | (unsigned)s;
    }
}

__global__ __launch_bounds__(256) void bucket_fill_k(
    const unsigned* __restrict__ binned, const int* __restrict__ bbase,
    int* __restrict__ rowptr, int* __restrict__ eidx,
    float* __restrict__ dinv, int n, int e) {
    __shared__ int cnt[256];
    __shared__ int cur[256];
    __shared__ int lds[256];
    __shared__ int sbuf[BCAP];
    int b = blockIdx.x, t = threadIdx.x;
    int beg = bbase[b], end = bbase[b + 1];
    int m = end - beg;
    cnt[t] = 0;
    __syncthreads();
    for (int q = t; q < m; q += 256) {
        unsigned r = binned[beg + q];
        atomicAdd(&cnt[r >> 17], 1);
    }
    __syncthreads();
    int v = cnt[t];
    lds[t] = v;
    __syncthreads();
    #pragma unroll
    for (int off = 1; off < 256; off <<= 1) {
        int u = (t >= off) ? lds[t - off] : 0;
        __syncthreads();
        lds[t] += u;
        __syncthreads();
    }
    int excl = lds[t] - v;
    int node = b * 256 + t;
    if (node < n) {
        rowptr[node] = beg + excl;
        dinv[node] = rsqrtf(1.0f + (float)v);
    }
    if (b == NB - 1 && t == 0) rowptr[n] = e;
    cur[t] = excl;
    __syncthreads();
    for (int q = t; q < m; q += 256) {
        unsigned r = binned[beg + q];
        int p = atomicAdd(&cur[r >> 17], 1);
        if (p < BCAP) sbuf[p] = (int)(r & 0x1FFFFu);
    }
    __syncthreads();
    for (int q = t; q < m; q += 256) eidx[beg + q] = sbuf[q];
}

// ------- W cast to fp16 in MFMA fragment order (once) -------
// frag idx for element (k,n): ct=n>>4, mrow=n&15, kc=k>>5, hi=(k&31)>>3, j=k&7
// idx = ((ct*NKC+kc)*64 + hi*16+mrow)*8 + j   (NKC = FIN/32)
static __device__ __forceinline__ void cast_frag(
    const float* __restrict__ W, _Float16* __restrict__ Wf,
    int FIN, int FOUT, int i) {
    int k = i / FOUT, n = i % FOUT;
    int ct = n >> 4, mrow = n & 15;
    int kc = k >> 5, hi = (k & 31) >> 3, j = k & 7;
    int NKC = FIN / 32;
    int idx = ((ct * NKC + kc) * 64 + hi * 16 + mrow) * 8 + j;
    Wf[idx] = (_Float16)W[(size_t)k * FOUT + n];
}

__global__ __launch_bounds__(256) void castW_k(
    const float* __restrict__ W1, const float* __restrict__ W2,
    const float* __restrict__ W3, _Float16* __restrict__ Wf1,
    _Float16* __restrict__ Wf2, _Float16* __restrict__ Wf3) {
    int i = blockIdx.x * 256 + threadIdx.x;
    if (i < 256 * 128) cast_frag(W1, Wf1, 256, 128, i);
    if (i < 128 * 128) cast_frag(W2, Wf2, 128, 128, i);
    if (i < 128 * 64)  cast_frag(W3, Wf3, 128, 64, i);
}

// ------- GEMM: G(fp16, chunk32-major) = (X@W)*dinv[row] -------
// block = 4 waves x 16 rows = 64 rows, all FOUT cols per wave.
// B (fragment-ordered) staged to LDS once (memcpy); one barrier total.
// fp16 input X is chunk32-major [FIN/32][n][32]; output G is chunk32-major
// [FOUT/32][n][32] (chunk = ct>>1 in the MFMA D layout).
template<typename TA, int FIN, int FOUT>
__global__ __launch_bounds__(256, 2) void gemm_ldsB_k(
    const TA* __restrict__ X, const _Float16* __restrict__ Wf,
    const float* __restrict__ dinv, _Float16* __restrict__ G, int n)
{
    constexpr int NKC = FIN / 32;        // k-chunks
    constexpr int NCT = FOUT / 16;       // col tiles (all owned by each wave)
    __shared__ _Float16 wS[FOUT * FIN];  // 64/32/16 KB

    const int tid  = threadIdx.x;
    const int wave = tid >> 6;
    const int lane = tid & 63;
    const int mrow = lane & 15;
    const int kq   = (lane >> 4) * 8;

    // stage fragment-ordered W -> LDS (contiguous memcpy)
    {
        const half8* s = (const half8*)Wf;
        half8* d = (half8*)wS;
        constexpr int TOT8 = FOUT * FIN / 8;
        #pragma unroll
        for (int i = tid; i < TOT8; i += 256) d[i] = s[i];
    }

    int r = blockIdx.x * 64 + wave * 16 + mrow;
    if (r > n - 1) r = n - 1;            // junk rows never stored

    // all A-loads upfront (independent, overlap the staging + barrier)
    half8 af[NKC];
    if constexpr (sizeof(TA) == 4) {
        // row-major fp32 input (layer 1: x)
        const float* xp = (const float*)X + (size_t)r * FIN + kq;
        float4 t0[NKC], t1[NKC];
        #pragma unroll
        for (int kc = 0; kc < NKC; ++kc) {
            t0[kc] = *(const float4*)(xp + kc * 32);
            t1[kc] = *(const float4*)(xp + kc * 32 + 4);
        }
        #pragma unroll
        for (int kc = 0; kc < NKC; ++kc) {
            float4 u0 = t0[kc], u1 = t1[kc];
            af[kc] = (half8){(_Float16)u0.x, (_Float16)u0.y, (_Float16)u0.z, (_Float16)u0.w,
                             (_Float16)u1.x, (_Float16)u1.y, (_Float16)u1.z, (_Float16)u1.w};
        }
    } else {
        // chunk32-major fp16 input [FIN/32][n][32]: k-elems kc*32+kq..+7 live
        // at chunk kc, offset kq — one aligned 16 B read
        const _Float16* xp = (const _Float16*)X;
        #pragma unroll
        for (int kc = 0; kc < NKC; ++kc)
            af[kc] = *(const half8*)(xp + ((size_t)kc * n + r) * 32 + kq);
    }

    __syncthreads();                     // the only barrier

    floatx4 acc[NCT];
    #pragma unroll
    for (int ct = 0; ct < NCT; ++ct) acc[ct] = (floatx4){0.f, 0.f, 0.f, 0.f};

    #pragma unroll
    for (int kc = 0; kc < NKC; ++kc) {
        #pragma unroll
        for (int ct = 0; ct < NCT; ++ct) {
            // stride-1 ds_read_b128: addr = ((ct*NKC+kc)*64 + lane)*16B
            half8 bf = *(const half8*)&wS[(((ct * NKC) + kc) * 64 + lane) * 8];
            acc[ct] = __builtin_amdgcn_mfma_f32_16x16x32_f16(af[kc], bf, acc[ct], 0, 0, 0);
        }
    }

    // D layout: col = lane&15, row = (lane>>4)*4 + reg  [m89/m91 verified]
    int rbase = blockIdx.x * 64 + wave * 16 + (lane >> 4) * 4;
    #pragma unroll
    for (int reg = 0; reg < 4; ++reg) {
        int rr = rbase + reg;
        if (rr < n) {
            float s = dinv[rr];
            #pragma unroll
            for (int ct = 0; ct < NCT; ++ct)
                G[((size_t)(ct >> 1) * n + rr) * 32 + (ct & 1) * 16 + mrow] =
                    (_Float16)(acc[ct][reg] * s);
        }
    }
}

// -------- Chunk32-major XCD-local gather --------
// g layout [NCHUNK][n][32] fp16: 64 B rows = one fully-used cache line per
// row-read (8 lanes x 8 B). blockIdx%8 -> (chunk, node-segment); consecutive
// blockIdx round-robin the 8 XCDs so each XCD gathers ONE 6.4 MB chunk table
// (vs 25.6 MB row-major) — L2 keeps most of it resident.
// Wave structure (proven row-major loop shape): 1 node per wave, octile
// o=lane>>3 is the edge slot, s=lane&7 covers feats 4s..4s+3. 64 ids loaded
// coalesced then shfl-broadcast; 2 row-loads in flight; octile butterfly
// reduce. Each wave iterates 4 nodes to amortize the prologue.
template<int NCHUNK, int NSPLIT, bool RELU, bool F32OUT>
__global__ __launch_bounds__(256) void gatherc32_k(
    const _Float16* __restrict__ g, const int* __restrict__ rowptr,
    const int* __restrict__ eidx, const float* __restrict__ dinv,
    const float* __restrict__ bias, void* __restrict__ outv, int n)
{
    static_assert(NCHUNK * NSPLIT == 8, "8 XCD groups");
    const int lane = threadIdx.x & 63;
    const int wave = threadIdx.x >> 6;
    const int o = lane >> 3;            // octile: edge slot
    const int s = lane & 7;             // feats 4s..4s+3 of this chunk

    const int cg = blockIdx.x & 7;      // -> XCD (HW round-robin)
    const int nb = blockIdx.x >> 3;
    const int chunk = cg % NCHUNK;
    const int split = cg / NCHUNK;
    const int seg = (n + NSPLIT - 1) / NSPLIT;
    const int n0 = split * seg;
    int nlim = n0 + seg; if (nlim > n) nlim = n;

    const half4v* __restrict__ g4 = (const half4v*)(g + (size_t)chunk * n * 32);
    const float4 bb = *(const float4*)(bias + chunk * 32 + 4 * s);

    for (int it = 0; it < 4; ++it) {
        const int node = n0 + nb * 16 + it * 4 + wave;   // wave-uniform
        if (node >= nlim) break;

        const int beg = rowptr[node];
        const int end = rowptr[node + 1];
        const float sc = dinv[node];

        floatx4 aA = {0.f, 0.f, 0.f, 0.f}, aB = aA;
        {   // self loop (counted once: only octile 0 adds)
            half4v v = g4[(size_t)node * 8 + s];
            if (o == 0) aA = h2f4(v);
        }

        for (int j0 = beg; j0 < end; j0 += 64) {
            int m = end - j0; if (m > 64) m = 64;
            int id = (lane < m) ? __builtin_nontemporal_load(eidx + j0 + lane) : 0;
            int t = 0;
            for (; t + 15 < m; t += 16) {          // 2 row-loads in flight
                int i0 = __shfl(id, t + o);
                int i1 = __shfl(id, t + 8 + o);
                half4v v0 = g4[(size_t)i0 * 8 + s];
                half4v v1 = g4[(size_t)i1 * 8 + s];
                aA += h2f4(v0); aB += h2f4(v1);
            }
            for (; t + 7 < m; t += 8) {
                int i0 = __shfl(id, t + o);
                aA += h2f4(g4[(size_t)i0 * 8 + s]);
            }
            if (t < m) {                           // partial last octet
                int e = t + o;
                int i0 = __shfl(id, e & 63);       // dead lanes: id=0, safe addr
                half4v v0 = g4[(size_t)i0 * 8 + s];
                if (e < m) aA += h2f4(v0);
            }
        }

        aA += aB;
        #pragma unroll
        for (int off = 8; off <= 32; off <<= 1) {  // reduce across 8 octiles
            aA.x += __shfl_xor(aA.x, off);
            aA.y += __shfl_xor(aA.y, off);
            aA.z += __shfl_xor(aA.z, off);
            aA.w += __shfl_xor(aA.w, off);
        }

        if (o == 0) {
            float o0 = fmaf(aA.x, sc, bb.x);
            float o1 = fmaf(aA.y, sc, bb.y);
            float o2 = fmaf(aA.z, sc, bb.z);
            float o3 = fmaf(aA.w, sc, bb.w);
            if (RELU) {
                o0 = fmaxf(o0, 0.f); o1 = fmaxf(o1, 0.f);
                o2 = fmaxf(o2, 0.f); o3 = fmaxf(o3, 0.f);
            }
            if constexpr (F32OUT) {
                // final output: row-major [n][NCHUNK*32] fp32 (harness layout)
                floatx4* p = (floatx4*)((float*)outv + (size_t)node * (NCHUNK * 32)
                                        + chunk * 32 + 4 * s);
                __builtin_nontemporal_store((floatx4){o0, o1, o2, o3}, p);
            } else {
                // chunk32-major fp16 out (next GEMM's A)
                half4v hv = {(_Float16)o0, (_Float16)o1, (_Float16)o2, (_Float16)o3};
                half4v* p = (half4v*)outv + ((size_t)chunk * n + node) * 8 + s;
                __builtin_nontemporal_store(hv, p);
            }
        }
    }
}

extern "C" void kernel_launch(void* const* d_in, const int* in_sizes, int n_in,
                              void* d_out, int out_size, void* d_ws, size_t ws_size,
                              hipStream_t stream) {
    const float* x  = (const float*)d_in[0];
    const int*   ei = (const int*)d_in[1];     // [2, E] int32
    const float* W1 = (const float*)d_in[2];
    const float* b1 = (const float*)d_in[3];
    const float* W2 = (const float*)d_in[4];
    const float* b2 = (const float*)d_in[5];
    const float* W3 = (const float*)d_in[6];
    const float* b3 = (const float*)d_in[7];
    float* out = (float*)d_out;

    const int N = NNODES;
    const int E = in_sizes[1] / 2;
    const int* srcI = ei;
    const int* dstI = ei + E;

    const int npb = (E + PB - 1) / PB;

    char* ws = (char*)d_ws;
    size_t p = 0;
    auto alloc = [&](size_t bytes) { void* r = ws + p; p = (p + bytes + 255) & ~(size_t)255; return r; };
    float*     dinv   = (float*)    alloc((size_t)N * 4);
    int*       rowptr = (int*)      alloc((size_t)(N + 1) * 4);
    int*       bbase  = (int*)      alloc((size_t)(NB + 1) * 4);
    int*       T      = (int*)      alloc((size_t)NB * 4);
    int*       H      = (int*)      alloc((size_t)npb * NB * 4);
    int*       O      = (int*)      alloc((size_t)npb * NB * 4);
    unsigned*  binned = (unsigned*) alloc((size_t)E * 4);
    int*       eidx   = (int*)      alloc((size_t)E * 4);
    _Float16*  Wf1    = (_Float16*) alloc((size_t)128 * 256 * 2);
    _Float16*  Wf2    = (_Float16*) alloc((size_t)128 * 128 * 2);
    _Float16*  Wf3    = (_Float16*) alloc((size_t)64 * 128 * 2);
    _Float16*  A      = (_Float16*) alloc((size_t)N * 128 * 2);
    _Float16*  Ch     = (_Float16*) alloc((size_t)N * 128 * 2);

    const int nb_gemm = (N + 63) / 64;                    // 1563 blocks, 64 rows each
    const int seg128  = (N + 1) / 2;                      // NSPLIT=2 node segments
    const int nb_g128 = ((seg128 + 15) / 16) * 8;         // 16 nodes/block x 8 groups
    const int seg64   = (N + 3) / 4;                      // NSPLIT=4 node segments
    const int nb_g64  = ((seg64 + 15) / 16) * 8;

    // ---- CSR build + weight prep ----
    blockhist_k<<<npb, 256, 0, stream>>>(dstI, H, E);
    castW_k<<<128, 256, 0, stream>>>(W1, W2, W3, Wf1, Wf2, Wf3);
    bucketscan_k<<<NB, 256, 0, stream>>>(H, O, T, npb);
    scanT_k<<<1, 512, 0, stream>>>(T, bbase, E);
    scatter_k<<<npb, 256, 0, stream>>>(srcI, dstI, O, bbase, binned, E);
    bucket_fill_k<<<NB, 256, 0, stream>>>(binned, bbase, rowptr, eidx, dinv, N, E);

    // ---- layer 1: FEAT=256 -> HID=128 ----
    gemm_ldsB_k<float, 256, 128><<<nb_gemm, 256, 0, stream>>>(x, Wf1, dinv, A, N);
    gatherc32_k<4, 2, true, false><<<nb_g128, 256, 0, stream>>>(A, rowptr, eidx, dinv, b1, Ch, N);

    // ---- layer 2: HID=128 -> HID=128 ----
    gemm_ldsB_k<_Float16, 128, 128><<<nb_gemm, 256, 0, stream>>>(Ch, Wf2, dinv, A, N);
    gatherc32_k<4, 2, true, false><<<nb_g128, 256, 0, stream>>>(A, rowptr, eidx, dinv, b2, Ch, N);

    // ---- layer 3: HID=128 -> OUT=64 ----
    gemm_ldsB_k<_Float16, 128, 64><<<nb_gemm, 256, 0, stream>>>(Ch, Wf3, dinv, A, N);
    gatherc32_k<2, 4, false, true><<<nb_g64, 256, 0, stream>>>(A, rowptr, eidx, dinv, b3, out, N);
}

// Round 3
// 452.326 us; speedup vs baseline: 1.3401x; 1.3324x over previous
//
#include <hip/hip_runtime.h>
#include <hip/hip_bf16.h>

// 3-layer GCN: per layer  out = relu(dinv .* segsum(dinv .* (X@W)) + b)
// fp16 pipeline: GEMMs via mfma_f32_16x16x32_f16 (f32 accum).
//  - GEMM: waves own DISJOINT 16-row strips x all FOUT cols; B staged to LDS
//    ONCE per block; W pre-stored in MFMA fragment order.
//  - Gather is ROW-MAJOR, one edge-visit per edge (r10/r11 proved feature-
//    chunking trades fetch for 4-8x edge-visit overhead at a losing rate:
//    equal-fetch chunk-32 ran 2.1x slower, VALU-time 27->75 us).
//    Quarter-wave geometry: 16 lanes x half8 (16 B) cover one 256 B row, so
//    each wave-load = 4 rows = 16 cache lines (2x round-0's half-wave 8 B
//    loads), 4-deep bursts put 64 lines in flight per wave, and shfl
//    broadcasts per edge are halved — attacks the issue/latency bound
//    (round-0: hbm 43%, VALU 42%, neither pipe saturated).
// CSR build = deterministic two-level counting sort, zero global atomics.

#define NNODES 100000
#define NB 391          // buckets of 256 nodes: ceil(100000/256)
#define PB 2048         // edges per partition block
#define BCAP 12288      // per-bucket LDS sort capacity (mean 4096, sd ~64)

typedef _Float16 half8  __attribute__((ext_vector_type(8)));
typedef _Float16 half4v __attribute__((ext_vector_type(4)));
typedef float    floatx4 __attribute__((ext_vector_type(4)));

static __device__ __forceinline__ floatx4 h2f4(half4v v) {
    return (floatx4){(float)v.x, (float)v.y, (float)v.z, (float)v.w};
}
static __device__ __forceinline__ floatx4 h2f4lo(half8 v) {
    return (floatx4){(float)v[0], (float)v[1], (float)v[2], (float)v[3]};
}
static __device__ __forceinline__ floatx4 h2f4hi(half8 v) {
    return (floatx4){(float)v[4], (float)v[5], (float)v[6], (float)v[7]};
}

// ---------------- CSR build: deterministic partition ----------------
__global__ __launch_bounds__(256) void blockhist_k(const int* __restrict__ dst,
                                                   int* __restrict__ H, int e) {
    __shared__ int h[NB];
    for (int q = threadIdx.x; q < NB; q += 256) h[q] = 0;
    __syncthreads();
    int base = blockIdx.x * PB;
    int lim = e - base; if (lim > PB) lim = PB;
    for (int i = threadIdx.x; i < lim; i += 256)
        atomicAdd(&h[dst[base + i] >> 8], 1);
    __syncthreads();
    for (int q = threadIdx.x; q < NB; q += 256)
        H[(size_t)blockIdx.x * NB + q] = h[q];
}

__global__ __launch_bounds__(256) void bucketscan_k(const int* __restrict__ H,
                                                    int* __restrict__ O,
                                                    int* __restrict__ T, int npb) {
    __shared__ int lds[256];
    int b = blockIdx.x, t = threadIdx.x;
    int running = 0;
    for (int c0 = 0; c0 < npb; c0 += 256) {
        int idx = c0 + t;
        int v = (idx < npb) ? H[(size_t)idx * NB + b] : 0;
        lds[t] = v;
        __syncthreads();
        #pragma unroll
        for (int off = 1; off < 256; off <<= 1) {
            int u = (t >= off) ? lds[t - off] : 0;
            __syncthreads();
            lds[t] += u;
            __syncthreads();
        }
        int excl = lds[t] - v + running;
        if (idx < npb) O[(size_t)idx * NB + b] = excl;
        running += lds[255];
        __syncthreads();
    }
    if (t == 0) T[b] = running;
}

__global__ __launch_bounds__(512) void scanT_k(const int* __restrict__ T,
                                               int* __restrict__ bbase, int e) {
    __shared__ int lds[512];
    int t = threadIdx.x;
    int v = (t < NB) ? T[t] : 0;
    lds[t] = v;
    __syncthreads();
    #pragma unroll
    for (int off = 1; off < 512; off <<= 1) {
        int u = (t >= off) ? lds[t - off] : 0;
        __syncthreads();
        lds[t] += u;
        __syncthreads();
    }
    if (t < NB) bbase[t] = lds[t] - v;
    if (t == 0) bbase[NB] = e;
}

__global__ __launch_bounds__(256) void scatter_k(const int* __restrict__ src,
                                                 const int* __restrict__ dst,
                                                 const int* __restrict__ O,
                                                 const int* __restrict__ bbase,
                                                 unsigned* __restrict__ binned, int e) {
    __shared__ int cur[NB];
    for (int q = threadIdx.x; q < NB; q += 256)
        cur[q] = bbase[q] + O[(size_t)blockIdx.x * NB + q];
    __syncthreads();
    int base = blockIdx.x * PB;
    int lim = e - base; if (lim > PB) lim = PB;
    for (int i = threadIdx.x; i < lim; i += 256) {
        int d = dst[base + i];
        int s = src[base + i];
        int p = atomicAdd(&cur[d >> 8], 1);
        binned[p] = ((unsigned)(d & 255) << 17) | (unsigned)s;
    }
}

__global__ __launch_bounds__(256) void bucket_fill_k(
    const unsigned* __restrict__ binned, const int* __restrict__ bbase,
    int* __restrict__ rowptr, int* __restrict__ eidx,
    float* __restrict__ dinv, int n, int e) {
    __shared__ int cnt[256];
    __shared__ int cur[256];
    __shared__ int lds[256];
    __shared__ int sbuf[BCAP];
    int b = blockIdx.x, t = threadIdx.x;
    int beg = bbase[b], end = bbase[b + 1];
    int m = end - beg;
    cnt[t] = 0;
    __syncthreads();
    for (int q = t; q < m; q += 256) {
        unsigned r = binned[beg + q];
        atomicAdd(&cnt[r >> 17], 1);
    }
    __syncthreads();
    int v = cnt[t];
    lds[t] = v;
    __syncthreads();
    #pragma unroll
    for (int off = 1; off < 256; off <<= 1) {
        int u = (t >= off) ? lds[t - off] : 0;
        __syncthreads();
        lds[t] += u;
        __syncthreads();
    }
    int excl = lds[t] - v;
    int node = b * 256 + t;
    if (node < n) {
        rowptr[node] = beg + excl;
        dinv[node] = rsqrtf(1.0f + (float)v);
    }
    if (b == NB - 1 && t == 0) rowptr[n] = e;
    cur[t] = excl;
    __syncthreads();
    for (int q = t; q < m; q += 256) {
        unsigned r = binned[beg + q];
        int p = atomicAdd(&cur[r >> 17], 1);
        if (p < BCAP) sbuf[p] = (int)(r & 0x1FFFFu);
    }
    __syncthreads();
    for (int q = t; q < m; q += 256) eidx[beg + q] = sbuf[q];
}

// ------- W cast to fp16 in MFMA fragment order (once) -------
// frag idx for element (k,n): ct=n>>4, mrow=n&15, kc=k>>5, hi=(k&31)>>3, j=k&7
// idx = ((ct*NKC+kc)*64 + hi*16+mrow)*8 + j   (NKC = FIN/32)
static __device__ __forceinline__ void cast_frag(
    const float* __restrict__ W, _Float16* __restrict__ Wf,
    int FIN, int FOUT, int i) {
    int k = i / FOUT, n = i % FOUT;
    int ct = n >> 4, mrow = n & 15;
    int kc = k >> 5, hi = (k & 31) >> 3, j = k & 7;
    int NKC = FIN / 32;
    int idx = ((ct * NKC + kc) * 64 + hi * 16 + mrow) * 8 + j;
    Wf[idx] = (_Float16)W[(size_t)k * FOUT + n];
}

__global__ __launch_bounds__(256) void castW_k(
    const float* __restrict__ W1, const float* __restrict__ W2,
    const float* __restrict__ W3, _Float16* __restrict__ Wf1,
    _Float16* __restrict__ Wf2, _Float16* __restrict__ Wf3) {
    int i = blockIdx.x * 256 + threadIdx.x;
    if (i < 256 * 128) cast_frag(W1, Wf1, 256, 128, i);
    if (i < 128 * 128) cast_frag(W2, Wf2, 128, 128, i);
    if (i < 128 * 64)  cast_frag(W3, Wf3, 128, 64, i);
}

// ------- GEMM: G(fp16) = (X@W)*dinv[row]; disjoint rows/wave, LDS-B once -------
// block = 4 waves x 16 rows = 64 rows, all FOUT cols per wave.
// B (fragment-ordered) staged to LDS once (memcpy); one barrier total.
template<typename TA, int FIN, int FOUT>
__global__ __launch_bounds__(256, 2) void gemm_ldsB_k(
    const TA* __restrict__ X, const _Float16* __restrict__ Wf,
    const float* __restrict__ dinv, _Float16* __restrict__ G, int n)
{
    constexpr int NKC = FIN / 32;        // k-chunks
    constexpr int NCT = FOUT / 16;       // col tiles (all owned by each wave)
    __shared__ _Float16 wS[FOUT * FIN];  // 64/32/16 KB

    const int tid  = threadIdx.x;
    const int wave = tid >> 6;
    const int lane = tid & 63;
    const int mrow = lane & 15;
    const int kq   = (lane >> 4) * 8;

    // stage fragment-ordered W -> LDS (contiguous memcpy)
    {
        const half8* s = (const half8*)Wf;
        half8* d = (half8*)wS;
        constexpr int TOT8 = FOUT * FIN / 8;
        #pragma unroll
        for (int i = tid; i < TOT8; i += 256) d[i] = s[i];
    }

    int r = blockIdx.x * 64 + wave * 16 + mrow;
    if (r > n - 1) r = n - 1;            // junk rows never stored

    // all A-loads upfront (independent, overlap the staging + barrier)
    half8 af[NKC];
    if constexpr (sizeof(TA) == 4) {
        const float* xp = (const float*)X + (size_t)r * FIN + kq;
        float4 t0[NKC], t1[NKC];
        #pragma unroll
        for (int kc = 0; kc < NKC; ++kc) {
            t0[kc] = *(const float4*)(xp + kc * 32);
            t1[kc] = *(const float4*)(xp + kc * 32 + 4);
        }
        #pragma unroll
        for (int kc = 0; kc < NKC; ++kc) {
            float4 u0 = t0[kc], u1 = t1[kc];
            af[kc] = (half8){(_Float16)u0.x, (_Float16)u0.y, (_Float16)u0.z, (_Float16)u0.w,
                             (_Float16)u1.x, (_Float16)u1.y, (_Float16)u1.z, (_Float16)u1.w};
        }
    } else {
        const _Float16* xp = (const _Float16*)X + (size_t)r * FIN + kq;
        #pragma unroll
        for (int kc = 0; kc < NKC; ++kc)
            af[kc] = *(const half8*)(xp + kc * 32);
    }

    __syncthreads();                     // the only barrier

    floatx4 acc[NCT];
    #pragma unroll
    for (int ct = 0; ct < NCT; ++ct) acc[ct] = (floatx4){0.f, 0.f, 0.f, 0.f};

    #pragma unroll
    for (int kc = 0; kc < NKC; ++kc) {
        #pragma unroll
        for (int ct = 0; ct < NCT; ++ct) {
            // stride-1 ds_read_b128: addr = ((ct*NKC+kc)*64 + lane)*16B
            half8 bf = *(const half8*)&wS[(((ct * NKC) + kc) * 64 + lane) * 8];
            acc[ct] = __builtin_amdgcn_mfma_f32_16x16x32_f16(af[kc], bf, acc[ct], 0, 0, 0);
        }
    }

    // D layout: col = lane&15, row = (lane>>4)*4 + reg  [m89/m91 verified]
    int rbase = blockIdx.x * 64 + wave * 16 + (lane >> 4) * 4;
    #pragma unroll
    for (int reg = 0; reg < 4; ++reg) {
        int rr = rbase + reg;
        if (rr < n) {
            float s = dinv[rr];
            #pragma unroll
            for (int ct = 0; ct < NCT; ++ct)
                G[(size_t)rr * FOUT + ct * 16 + mrow] = (_Float16)(acc[ct][reg] * s);
        }
    }
}

// -------- CSR gather segsum, F=128: quarter-wave, half8 (16 B) row loads --------
// Quarter q = edge slot, f = lane&15 covers feats 8f..8f+7. One wave-load = 4
// rows x 256 B = 16 cache lines; 4-deep burst = 64 lines in flight per wave.
template<bool RELU>
__global__ __launch_bounds__(256) void gatherq128_k(
    const _Float16* __restrict__ g, const int* __restrict__ rowptr,
    const int* __restrict__ eidx, const float* __restrict__ dinv,
    const float* __restrict__ bias, _Float16* __restrict__ out, int n)
{
    const int wave = threadIdx.x >> 6;
    const int lane = threadIdx.x & 63;
    const int q = lane >> 4;            // edge slot within burst
    const int f = lane & 15;            // feats 8f..8f+7
    const int node = blockIdx.x * 4 + wave;
    if (node >= n) return;

    const int beg = rowptr[node];
    const int end = rowptr[node + 1];

    const half8* g8 = (const half8*)g;  // row stride = 16 half8
    floatx4 aA0 = {0.f,0.f,0.f,0.f}, aA1 = aA0, aB0 = aA0, aB1 = aA0;
    {   // self loop (added once: only quarter 0)
        half8 v = g8[(size_t)node * 16 + f];
        if (q == 0) { aA0 = h2f4lo(v); aA1 = h2f4hi(v); }
    }

    for (int j0 = beg; j0 < end; j0 += 64) {
        int m = end - j0; if (m > 64) m = 64;
        int id = (lane < m) ? __builtin_nontemporal_load(eidx + j0 + lane) : 0;
        int t = 0;
        for (; t + 15 < m; t += 16) {   // 4 row-loads (16 edges) in flight
            int i0 = __shfl(id, t + q);
            int i1 = __shfl(id, t + 4 + q);
            int i2 = __shfl(id, t + 8 + q);
            int i3 = __shfl(id, t + 12 + q);
            half8 v0 = g8[(size_t)i0 * 16 + f];
            half8 v1 = g8[(size_t)i1 * 16 + f];
            half8 v2 = g8[(size_t)i2 * 16 + f];
            half8 v3 = g8[(size_t)i3 * 16 + f];
            aA0 += h2f4lo(v0); aA1 += h2f4hi(v0);
            aB0 += h2f4lo(v1); aB1 += h2f4hi(v1);
            aA0 += h2f4lo(v2); aA1 += h2f4hi(v2);
            aB0 += h2f4lo(v3); aB1 += h2f4hi(v3);
        }
        for (; t < m; t += 4) {         // tail: 4 edges per wave-load, guarded
            int e = t + q;
            int i0 = __shfl(id, e & 63);  // dead slots: id=0, safe addr
            half8 v0 = g8[(size_t)i0 * 16 + f];
            if (e < m) { aA0 += h2f4lo(v0); aA1 += h2f4hi(v0); }
        }
    }

    aA0 += aB0; aA1 += aB1;
    #pragma unroll
    for (int off = 16; off <= 32; off <<= 1) {   // reduce across quarters
        aA0.x += __shfl_xor(aA0.x, off);
        aA0.y += __shfl_xor(aA0.y, off);
        aA0.z += __shfl_xor(aA0.z, off);
        aA0.w += __shfl_xor(aA0.w, off);
        aA1.x += __shfl_xor(aA1.x, off);
        aA1.y += __shfl_xor(aA1.y, off);
        aA1.z += __shfl_xor(aA1.z, off);
        aA1.w += __shfl_xor(aA1.w, off);
    }

    if (q == 0) {
        float sc = dinv[node];
        float4 b0 = *(const float4*)(bias + 8 * f);
        float4 b1 = *(const float4*)(bias + 8 * f + 4);
        float o0 = fmaf(aA0.x, sc, b0.x);
        float o1 = fmaf(aA0.y, sc, b0.y);
        float o2 = fmaf(aA0.z, sc, b0.z);
        float o3 = fmaf(aA0.w, sc, b0.w);
        float o4 = fmaf(aA1.x, sc, b1.x);
        float o5 = fmaf(aA1.y, sc, b1.y);
        float o6 = fmaf(aA1.z, sc, b1.z);
        float o7 = fmaf(aA1.w, sc, b1.w);
        if (RELU) {
            o0 = fmaxf(o0, 0.f); o1 = fmaxf(o1, 0.f);
            o2 = fmaxf(o2, 0.f); o3 = fmaxf(o3, 0.f);
            o4 = fmaxf(o4, 0.f); o5 = fmaxf(o5, 0.f);
            o6 = fmaxf(o6, 0.f); o7 = fmaxf(o7, 0.f);
        }
        half8 hv = {(_Float16)o0, (_Float16)o1, (_Float16)o2, (_Float16)o3,
                    (_Float16)o4, (_Float16)o5, (_Float16)o6, (_Float16)o7};
        __builtin_nontemporal_store(hv, (half8*)out + (size_t)node * 16 + f);
    }
}

// -------- F=64 variant: quarter-wave, half4 (8 B) row loads, f32 out --------
__global__ __launch_bounds__(256) void gatherq64_k(
    const _Float16* __restrict__ g, const int* __restrict__ rowptr,
    const int* __restrict__ eidx, const float* __restrict__ dinv,
    const float* __restrict__ bias, float* __restrict__ out, int n)
{
    const int wave = threadIdx.x >> 6;
    const int lane = threadIdx.x & 63;
    const int q = lane >> 4;            // edge slot
    const int f = lane & 15;            // feats 4f..4f+3
    const int node = blockIdx.x * 4 + wave;
    if (node >= n) return;

    const int beg = rowptr[node];
    const int end = rowptr[node + 1];

    const half4v* g4 = (const half4v*)g;   // row stride = 16 half4
    floatx4 aA = {0.f,0.f,0.f,0.f}, aB = aA;
    {
        half4v v = g4[(size_t)node * 16 + f];
        if (q == 0) aA = h2f4(v);
    }

    for (int j0 = beg; j0 < end; j0 += 64) {
        int m = end - j0; if (m > 64) m = 64;
        int id = (lane < m) ? __builtin_nontemporal_load(eidx + j0 + lane) : 0;
        int t = 0;
        for (; t + 15 < m; t += 16) {
            int i0 = __shfl(id, t + q);
            int i1 = __shfl(id, t + 4 + q);
            int i2 = __shfl(id, t + 8 + q);
            int i3 = __shfl(id, t + 12 + q);
            half4v v0 = g4[(size_t)i0 * 16 + f];
            half4v v1 = g4[(size_t)i1 * 16 + f];
            half4v v2 = g4[(size_t)i2 * 16 + f];
            half4v v3 = g4[(size_t)i3 * 16 + f];
            aA += h2f4(v0); aB += h2f4(v1);
            aA += h2f4(v2); aB += h2f4(v3);
        }
        for (; t < m; t += 4) {
            int e = t + q;
            int i0 = __shfl(id, e & 63);
            half4v v0 = g4[(size_t)i0 * 16 + f];
            if (e < m) aA += h2f4(v0);
        }
    }

    aA += aB;
    #pragma unroll
    for (int off = 16; off <= 32; off <<= 1) {
        aA.x += __shfl_xor(aA.x, off);
        aA.y += __shfl_xor(aA.y, off);
        aA.z += __shfl_xor(aA.z, off);
        aA.w += __shfl_xor(aA.w, off);
    }

    if (q == 0) {
        float sc = dinv[node];
        float4 bb = *(const float4*)(bias + 4 * f);
        floatx4 o;
        o.x = fmaf(aA.x, sc, bb.x);
        o.y = fmaf(aA.y, sc, bb.y);
        o.z = fmaf(aA.z, sc, bb.z);
        o.w = fmaf(aA.w, sc, bb.w);
        __builtin_nontemporal_store(o, (floatx4*)(out + (size_t)node * 64 + 4 * f));
    }
}

extern "C" void kernel_launch(void* const* d_in, const int* in_sizes, int n_in,
                              void* d_out, int out_size, void* d_ws, size_t ws_size,
                              hipStream_t stream) {
    const float* x  = (const float*)d_in[0];
    const int*   ei = (const int*)d_in[1];     // [2, E] int32
    const float* W1 = (const float*)d_in[2];
    const float* b1 = (const float*)d_in[3];
    const float* W2 = (const float*)d_in[4];
    const float* b2 = (const float*)d_in[5];
    const float* W3 = (const float*)d_in[6];
    const float* b3 = (const float*)d_in[7];
    float* out = (float*)d_out;

    const int N = NNODES;
    const int E = in_sizes[1] / 2;
    const int* srcI = ei;
    const int* dstI = ei + E;

    const int npb = (E + PB - 1) / PB;

    char* ws = (char*)d_ws;
    size_t p = 0;
    auto alloc = [&](size_t bytes) { void* r = ws + p; p = (p + bytes + 255) & ~(size_t)255; return r; };
    float*     dinv   = (float*)    alloc((size_t)N * 4);
    int*       rowptr = (int*)      alloc((size_t)(N + 1) * 4);
    int*       bbase  = (int*)      alloc((size_t)(NB + 1) * 4);
    int*       T      = (int*)      alloc((size_t)NB * 4);
    int*       H      = (int*)      alloc((size_t)npb * NB * 4);
    int*       O      = (int*)      alloc((size_t)npb * NB * 4);
    unsigned*  binned = (unsigned*) alloc((size_t)E * 4);
    int*       eidx   = (int*)      alloc((size_t)E * 4);
    _Float16*  Wf1    = (_Float16*) alloc((size_t)128 * 256 * 2);
    _Float16*  Wf2    = (_Float16*) alloc((size_t)128 * 128 * 2);
    _Float16*  Wf3    = (_Float16*) alloc((size_t)64 * 128 * 2);
    _Float16*  A      = (_Float16*) alloc((size_t)N * 128 * 2);
    _Float16*  Ch     = (_Float16*) alloc((size_t)N * 128 * 2);

    const int nb_node4 = (N + 3) / 4;
    const int nb_gemm  = (N + 63) / 64;    // 1563 blocks, 64 rows each

    // ---- CSR build + weight prep ----
    blockhist_k<<<npb, 256, 0, stream>>>(dstI, H, E);
    castW_k<<<128, 256, 0, stream>>>(W1, W2, W3, Wf1, Wf2, Wf3);
    bucketscan_k<<<NB, 256, 0, stream>>>(H, O, T, npb);
    scanT_k<<<1, 512, 0, stream>>>(T, bbase, E);
    scatter_k<<<npb, 256, 0, stream>>>(srcI, dstI, O, bbase, binned, E);
    bucket_fill_k<<<NB, 256, 0, stream>>>(binned, bbase, rowptr, eidx, dinv, N, E);

    // ---- layer 1: FEAT=256 -> HID=128 ----
    gemm_ldsB_k<float, 256, 128><<<nb_gemm, 256, 0, stream>>>(x, Wf1, dinv, A, N);
    gatherq128_k<true><<<nb_node4, 256, 0, stream>>>(A, rowptr, eidx, dinv, b1, Ch, N);

    // ---- layer 2: HID=128 -> HID=128 ----
    gemm_ldsB_k<_Float16, 128, 128><<<nb_gemm, 256, 0, stream>>>(Ch, Wf2, dinv, A, N);
    gatherq128_k<true><<<nb_node4, 256, 0, stream>>>(A, rowptr, eidx, dinv, b2, Ch, N);

    // ---- layer 3: HID=128 -> OUT=64 ----
    gemm_ldsB_k<_Float16, 128, 64><<<nb_gemm, 256, 0, stream>>>(Ch, Wf3, dinv, A, N);
    gatherq64_k<<<nb_node4, 256, 0, stream>>>(A, rowptr, eidx, dinv, b3, out, N);
}